// Round 1
// baseline (759.243 us; speedup 1.0000x reference)
//
#include <hip/hip_runtime.h>

#define BSZ   65536
#define KDIM  1024
#define NOUT  15
#define NEXP  10
#define NROWS 300    // 150 expert rows (e*15+o) then 150 gate rows
#define NPAD  304
#define NTILES 19
#define BM    128
#define BK    64
#define LDK   72     // padded LDS stride in bf16 elems (64+8 -> 2-way bank alias, free)

typedef short bf16x8 __attribute__((ext_vector_type(8)));
typedef float f32x4  __attribute__((ext_vector_type(4)));

// round-to-nearest-even fp32 -> bf16, packed pair into one dword
__device__ __forceinline__ unsigned f2bf2(float a, float b) {
    unsigned ua = __float_as_uint(a);
    unsigned ub = __float_as_uint(b);
    ua = (ua + 0x7FFFu + ((ua >> 16) & 1u)) >> 16;
    ub = (ub + 0x7FFFu + ((ub >> 16) & 1u)) & 0xFFFF0000u;
    return ua | ub;
}

__global__ void __launch_bounds__(256, 2)
moe_kernel(const float* __restrict__ x,
           const float* __restrict__ ew,
           const float* __restrict__ eb,
           const float* __restrict__ gw,
           const float* __restrict__ gb,
           float* __restrict__ out)
{
    __shared__ union {
        struct { short xs[BM][LDK]; short ws[NPAD][LDK]; } st; // 62208 B
        float ep[4][16][305];                                   // 78080 B (max)
    } sm;

    const int tid  = threadIdx.x;
    const int wv   = tid >> 6;
    const int lane = tid & 63;
    const int lq   = lane >> 4;   // quad (k-offset selector for A/B frags)
    const int lr   = lane & 15;   // row-within-tile (A) / col (B, C/D)
    const int row0 = blockIdx.x * BM;

    f32x4 acc[2][NTILES];
    #pragma unroll
    for (int m = 0; m < 2; ++m)
        #pragma unroll
        for (int n = 0; n < NTILES; ++n)
            acc[m][n] = (f32x4){0.f, 0.f, 0.f, 0.f};

    for (int kk = 0; kk < KDIM; kk += BK) {
        // ---- stage X tile: BM x BK fp32 -> bf16 LDS (8 float4 per thread) ----
        #pragma unroll
        for (int i = 0; i < (BM * BK / 4) / 256; ++i) {
            int c  = tid + i * 256;
            int r  = c >> 4, c4 = c & 15;
            const float4 v = *(const float4*)(x + (size_t)(row0 + r) * KDIM + kk + c4 * 4);
            *(uint2*)&sm.st.xs[r][c4 * 4] = make_uint2(f2bf2(v.x, v.y), f2bf2(v.z, v.w));
        }
        // ---- stage W tile: NPAD x BK fp32 -> bf16 LDS (19 float4 per thread) ----
        #pragma unroll
        for (int i = 0; i < (NPAD * BK / 4) / 256; ++i) {
            int c  = tid + i * 256;
            int r  = c >> 4, c4 = c & 15;
            float4 v;
            if (r < 150)      v = *(const float4*)(ew + (size_t)r * KDIM + kk + c4 * 4);
            else if (r < 300) v = *(const float4*)(gw + (size_t)(r - 150) * KDIM + kk + c4 * 4);
            else              v = make_float4(0.f, 0.f, 0.f, 0.f);
            *(uint2*)&sm.st.ws[r][c4 * 4] = make_uint2(f2bf2(v.x, v.y), f2bf2(v.z, v.w));
        }
        __syncthreads();

        // ---- MFMA: per wave, 2 m-tiles x 19 n-tiles x 2 k-steps ----
        #pragma unroll
        for (int kt = 0; kt < 2; ++kt) {
            bf16x8 a0 = *(const bf16x8*)&sm.st.xs[wv * 32 +      lr][kt * 32 + lq * 8];
            bf16x8 a1 = *(const bf16x8*)&sm.st.xs[wv * 32 + 16 + lr][kt * 32 + lq * 8];
            #pragma unroll
            for (int nt = 0; nt < NTILES; ++nt) {
                bf16x8 bfr = *(const bf16x8*)&sm.st.ws[nt * 16 + lr][kt * 32 + lq * 8];
                acc[0][nt] = __builtin_amdgcn_mfma_f32_16x16x32_bf16(a0, bfr, acc[0][nt], 0, 0, 0);
                acc[1][nt] = __builtin_amdgcn_mfma_f32_16x16x32_bf16(a1, bfr, acc[1][nt], 0, 0, 0);
            }
        }
        __syncthreads();
    }

    // ---- epilogue: per m-tile, dump acc to per-wave LDS scratch, then softmax ----
    #pragma unroll 1
    for (int mt = 0; mt < 2; ++mt) {
        // C/D layout: col = lane&15, row = quad*4 + reg  [m89-verified]
        #pragma unroll
        for (int nt = 0; nt < NTILES; ++nt)
            #pragma unroll
            for (int r = 0; r < 4; ++r)
                sm.ep[wv][lq * 4 + r][nt * 16 + lr] = acc[mt][nt][r];
        __syncthreads();

        for (int t = lane; t < 16 * NOUT; t += 64) {
            int row = t / NOUT, o = t % NOUT;
            float miu[NEXP], xi[NEXP];
            float mx = -1e30f;
            #pragma unroll
            for (int e = 0; e < NEXP; ++e) {
                miu[e] = sm.ep[wv][row][e * NOUT + o]       + eb[e * NOUT + o];
                xi[e]  = sm.ep[wv][row][150 + e * NOUT + o] + gb[e * NOUT + o];
                mx = fmaxf(mx, xi[e]);
            }
            float s = 0.f, v = 0.f;
            #pragma unroll
            for (int e = 0; e < NEXP; ++e) {
                float g = __expf(xi[e] - mx);
                s += g;
                v += g * miu[e];
            }
            out[(size_t)(row0 + wv * 32 + mt * 16 + row) * NOUT + o] = v / s;
        }
        __syncthreads();
    }
}

extern "C" void kernel_launch(void* const* d_in, const int* in_sizes, int n_in,
                              void* d_out, int out_size, void* d_ws, size_t ws_size,
                              hipStream_t stream) {
    const float* x  = (const float*)d_in[0];
    const float* ew = (const float*)d_in[1];
    const float* eb = (const float*)d_in[2];
    const float* gw = (const float*)d_in[3];
    const float* gb = (const float*)d_in[4];
    float* out = (float*)d_out;
    moe_kernel<<<BSZ / BM, 256, 0, stream>>>(x, ew, eb, gw, gb, out);
}

// Round 2
// 539.753 us; speedup vs baseline: 1.4066x; 1.4066x over previous
//
#include <hip/hip_runtime.h>

#define KDIM  1024
#define NOUT  15
#define NEXP  10
#define BM    128
#define BK    64
#define LDK   68     // bf16 elems: 64 + 4 pad -> 136 B row stride (34 dwords), conflict-free 16-lane column reads
#define WROWS 320    // staged weight rows: 300 real (150 expert + 150 gate), 20 zero pad -> 20 n-tiles
#define SCOLS 312    // epilogue scratch stride (fp32): 312 % 32 = 24 -> max 2-way bank alias on dump

typedef short bf16x8 __attribute__((ext_vector_type(8)));
typedef float f32x4  __attribute__((ext_vector_type(4)));

// round-to-nearest-even fp32 -> bf16, packed pair into one dword
__device__ __forceinline__ unsigned f2bf2(float a, float b) {
    unsigned ua = __float_as_uint(a);
    unsigned ub = __float_as_uint(b);
    ua = (ua + 0x7FFFu + ((ua >> 16) & 1u)) >> 16;
    ub = (ub + 0x7FFFu + ((ub >> 16) & 1u)) & 0xFFFF0000u;
    return ua | ub;
}

__global__ void __launch_bounds__(512, 2)
moe_kernel(const float* __restrict__ x,
           const float* __restrict__ ew,
           const float* __restrict__ eb,
           const float* __restrict__ gw,
           const float* __restrict__ gb,
           float* __restrict__ out)
{
    __shared__ union {
        struct { short xs[BM][LDK]; short ws[WROWS][LDK]; } st; // 17408 + 43520 = 60928 B
        float ep[64][SCOLS];                                     // 79872 B (union max)
    } sm;

    const int tid  = threadIdx.x;
    const int wv   = tid >> 6;
    const int lane = tid & 63;
    const int lq   = lane >> 4;   // quad: k-offset selector (A/B), row-group (C/D)
    const int lr   = lane & 15;   // A row / B col / C col within 16-tile
    const int mw   = wv >> 2;     // 0..1 : which 64-row half this wave computes
    const int nw   = wv & 3;      // 0..3 : which 5 n-tiles this wave computes
    const size_t row0 = (size_t)blockIdx.x * BM;

    f32x4 acc[4][5];
    #pragma unroll
    for (int mi = 0; mi < 4; ++mi)
        #pragma unroll
        for (int ni = 0; ni < 5; ++ni)
            acc[mi][ni] = (f32x4){0.f, 0.f, 0.f, 0.f};

    for (int kk = 0; kk < KDIM; kk += BK) {
        // ---- stage X tile: 128 x 64 fp32 -> bf16 (2048 float4, 4/thread) ----
        #pragma unroll
        for (int i = 0; i < 4; ++i) {
            int c = tid + i * 512;
            int r = c >> 4, c4 = c & 15;
            const float4 v = *(const float4*)(x + (row0 + r) * KDIM + kk + c4 * 4);
            *(uint2*)&sm.st.xs[r][c4 * 4] = make_uint2(f2bf2(v.x, v.y), f2bf2(v.z, v.w));
        }
        // ---- stage W tile: 320 x 64 fp32 -> bf16 (5120 float4, 10/thread) ----
        #pragma unroll
        for (int i = 0; i < 10; ++i) {
            int c = tid + i * 512;
            int r = c >> 4, c4 = c & 15;
            float4 v;
            if (r < 150)      v = *(const float4*)(ew + (size_t)r * KDIM + kk + c4 * 4);
            else if (r < 300) v = *(const float4*)(gw + (size_t)(r - 150) * KDIM + kk + c4 * 4);
            else              v = make_float4(0.f, 0.f, 0.f, 0.f);
            *(uint2*)&sm.st.ws[r][c4 * 4] = make_uint2(f2bf2(v.x, v.y), f2bf2(v.z, v.w));
        }
        __syncthreads();

        // ---- MFMA: each wave 4 m-subtiles x 5 n-tiles, B-frag reused over 4 m ----
        #pragma unroll
        for (int kt = 0; kt < 2; ++kt) {
            bf16x8 a[4];
            #pragma unroll
            for (int mi = 0; mi < 4; ++mi)
                a[mi] = *(const bf16x8*)&sm.st.xs[mw * 64 + mi * 16 + lr][kt * 32 + lq * 8];
            #pragma unroll
            for (int ni = 0; ni < 5; ++ni) {
                bf16x8 b = *(const bf16x8*)&sm.st.ws[(nw * 5 + ni) * 16 + lr][kt * 32 + lq * 8];
                #pragma unroll
                for (int mi = 0; mi < 4; ++mi)
                    acc[mi][ni] = __builtin_amdgcn_mfma_f32_16x16x32_bf16(a[mi], b, acc[mi][ni], 0, 0, 0);
            }
        }
        __syncthreads();  // also protects epilogue's first scratch dump (overlays ws)
    }

    // ---- epilogue: two 64-row phases through LDS scratch ----
    #pragma unroll 1
    for (int g = 0; g < 2; ++g) {
        if (mw == g) {
            // C/D layout: col = lane&15, row = quad*4 + reg  [m89-verified]
            #pragma unroll
            for (int ni = 0; ni < 5; ++ni) {
                int nc = (nw * 5 + ni) * 16;
                if (nc < 300) {   // tile 19 is pure padding; cols 300..303 of tile 18 are zeros, never read
                    #pragma unroll
                    for (int mi = 0; mi < 4; ++mi)
                        #pragma unroll
                        for (int r = 0; r < 4; ++r)
                            sm.ep[mi * 16 + lq * 4 + r][nc + lr] = acc[mi][ni][r];
                }
            }
        }
        __syncthreads();

        // 64 rows x 15 outputs = 960 softmax tasks over 512 threads
        #pragma unroll 1
        for (int t = tid; t < 64 * NOUT; t += 512) {
            int row = t / NOUT, o = t % NOUT;
            float xi[NEXP];
            float miu_v[NEXP];
            float mx = -1e30f;
            #pragma unroll
            for (int e = 0; e < NEXP; ++e) {
                miu_v[e] = sm.ep[row][e * NOUT + o]       + eb[e * NOUT + o];
                xi[e]    = sm.ep[row][150 + e * NOUT + o] + gb[e * NOUT + o];
                mx = fmaxf(mx, xi[e]);
            }
            float s = 0.f, v = 0.f;
            #pragma unroll
            for (int e = 0; e < NEXP; ++e) {
                float g2 = __expf(xi[e] - mx);
                s += g2;
                v += g2 * miu_v[e];
            }
            out[(row0 + g * 64 + row) * NOUT + o] = v / s;
        }
        __syncthreads();  // phase-0 scratch reads done before phase-1 dump
    }
}

extern "C" void kernel_launch(void* const* d_in, const int* in_sizes, int n_in,
                              void* d_out, int out_size, void* d_ws, size_t ws_size,
                              hipStream_t stream) {
    const float* x  = (const float*)d_in[0];
    const float* ew = (const float*)d_in[1];
    const float* eb = (const float*)d_in[2];
    const float* gw = (const float*)d_in[3];
    const float* gb = (const float*)d_in[4];
    float* out = (float*)d_out;
    moe_kernel<<<65536 / BM, 512, 0, stream>>>(x, ew, eb, gw, gb, out);
}

// Round 3
// 509.403 us; speedup vs baseline: 1.4905x; 1.0596x over previous
//
#include <hip/hip_runtime.h>

#define KDIM  1024
#define NOUT  15
#define NEXP  10
#define BM    128
#define BK    64
#define LDK   72      // bf16 elems; 144 B row stride -> 16B-aligned rows, conflict-free staging writes
#define WROWS 320     // 150 expert rows + 150 gate rows + 20 zero pad -> 20 n-tiles
#define NKS   16      // KDIM / BK
#define SCOLS 312     // epilogue scratch stride (fp32)
#define WSLAB (WROWS * BK)   // bf16 elems per k-slice in workspace

typedef short bf16x8 __attribute__((ext_vector_type(8)));
typedef float f32x4  __attribute__((ext_vector_type(4)));

// round-to-nearest-even fp32 -> bf16, packed pair into one dword
__device__ __forceinline__ unsigned f2bf2(float a, float b) {
    unsigned ua = __float_as_uint(a);
    unsigned ub = __float_as_uint(b);
    ua = (ua + 0x7FFFu + ((ua >> 16) & 1u)) >> 16;
    ub = (ub + 0x7FFFu + ((ub >> 16) & 1u)) & 0xFFFF0000u;
    return ua | ub;
}

// ---- pre-pass: expert_w & gate_w fp32 -> bf16 workspace, layout [NKS][WROWS][BK] ----
__global__ void wconv_kernel(const float* __restrict__ ew,
                             const float* __restrict__ gw,
                             unsigned short* __restrict__ ws)
{
    int idx = blockIdx.x * 256 + threadIdx.x;   // 0 .. 320*128-1
    int r   = idx >> 7;                         // weight row 0..319
    int c8  = (idx & 127) * 8;                  // col 0..1016, step 8
    float4 v0 = {0.f,0.f,0.f,0.f}, v1 = {0.f,0.f,0.f,0.f};
    if (r < 150) {
        v0 = *(const float4*)(ew + r * KDIM + c8);
        v1 = *(const float4*)(ew + r * KDIM + c8 + 4);
    } else if (r < 300) {
        v0 = *(const float4*)(gw + (r - 150) * KDIM + c8);
        v1 = *(const float4*)(gw + (r - 150) * KDIM + c8 + 4);
    }
    uint4 o;
    o.x = f2bf2(v0.x, v0.y); o.y = f2bf2(v0.z, v0.w);
    o.z = f2bf2(v1.x, v1.y); o.w = f2bf2(v1.z, v1.w);
    *(uint4*)(ws + (c8 >> 6) * WSLAB + r * BK + (c8 & 63)) = o;
}

__global__ void __launch_bounds__(512, 2)
moe_kernel(const float* __restrict__ x,
           const unsigned short* __restrict__ wsrc,
           const float* __restrict__ eb,
           const float* __restrict__ gb,
           float* __restrict__ out)
{
    __shared__ union {
        struct { short xs[BM][LDK]; short ws[WROWS][LDK]; } st; // (128+320)*144 = 64512 B
        float ep[64][SCOLS];                                     // 79872 B (union max) -> 2 blocks/CU
    } sm;

    const int tid  = threadIdx.x;
    const int wv   = tid >> 6;
    const int lane = tid & 63;
    const int lq   = lane >> 4;
    const int lr   = lane & 15;
    const int mw   = wv >> 2;     // 0..1 : 64-row half
    const int nw   = wv & 3;      // 0..3 : 5 n-tiles each
    const size_t row0 = (size_t)blockIdx.x * BM;

    f32x4 acc[4][5];
    #pragma unroll
    for (int mi = 0; mi < 4; ++mi)
        #pragma unroll
        for (int ni = 0; ni < 5; ++ni)
            acc[mi][ni] = (f32x4){0.f, 0.f, 0.f, 0.f};

    float4 xv[4];
    uint4  wv4[5];

    // ---- prologue: load + store k-slice 0 ----
    #pragma unroll
    for (int i = 0; i < 4; ++i) {
        int c = tid + i * 512;
        xv[i] = *(const float4*)(x + (row0 + (c >> 4)) * KDIM + (c & 15) * 4);
    }
    #pragma unroll
    for (int i = 0; i < 5; ++i)
        wv4[i] = *(const uint4*)(wsrc + (tid + i * 512) * 8);
    #pragma unroll
    for (int i = 0; i < 4; ++i) {
        int c = tid + i * 512;
        *(uint2*)&sm.st.xs[c >> 4][(c & 15) * 4] =
            make_uint2(f2bf2(xv[i].x, xv[i].y), f2bf2(xv[i].z, xv[i].w));
    }
    #pragma unroll
    for (int i = 0; i < 5; ++i) {
        int idx = tid + i * 512;
        *(uint4*)&sm.st.ws[idx >> 3][(idx & 7) * 8] = wv4[i];
    }
    __syncthreads();

    // ---- pipelined K loop: prefetch k+1 while MFMAing k ----
    #pragma unroll 1
    for (int ks = 0; ks < NKS; ++ks) {
        const int kn = ks + 1;
        if (kn < NKS) {
            #pragma unroll
            for (int i = 0; i < 4; ++i) {
                int c = tid + i * 512;
                xv[i] = *(const float4*)(x + (row0 + (c >> 4)) * KDIM + kn * BK + (c & 15) * 4);
            }
            #pragma unroll
            for (int i = 0; i < 5; ++i)
                wv4[i] = *(const uint4*)(wsrc + kn * WSLAB + (tid + i * 512) * 8);
        }

        #pragma unroll
        for (int kt = 0; kt < 2; ++kt) {
            bf16x8 a[4];
            #pragma unroll
            for (int mi = 0; mi < 4; ++mi)
                a[mi] = *(const bf16x8*)&sm.st.xs[mw * 64 + mi * 16 + lr][kt * 32 + lq * 8];
            #pragma unroll
            for (int ni = 0; ni < 5; ++ni) {
                bf16x8 b = *(const bf16x8*)&sm.st.ws[(nw * 5 + ni) * 16 + lr][kt * 32 + lq * 8];
                #pragma unroll
                for (int mi = 0; mi < 4; ++mi)
                    acc[mi][ni] = __builtin_amdgcn_mfma_f32_16x16x32_bf16(a[mi], b, acc[mi][ni], 0, 0, 0);
            }
        }
        __syncthreads();

        if (kn < NKS) {
            #pragma unroll
            for (int i = 0; i < 4; ++i) {
                int c = tid + i * 512;
                *(uint2*)&sm.st.xs[c >> 4][(c & 15) * 4] =
                    make_uint2(f2bf2(xv[i].x, xv[i].y), f2bf2(xv[i].z, xv[i].w));
            }
            #pragma unroll
            for (int i = 0; i < 5; ++i) {
                int idx = tid + i * 512;
                *(uint4*)&sm.st.ws[idx >> 3][(idx & 7) * 8] = wv4[i];
            }
        }
        __syncthreads();
    }

    // ---- epilogue: two 64-row phases through LDS scratch ----
    #pragma unroll 1
    for (int g = 0; g < 2; ++g) {
        if (mw == g) {
            // C/D layout: col = lane&15, row = quad*4 + reg  [m89-verified]
            #pragma unroll
            for (int ni = 0; ni < 5; ++ni) {
                int nc = (nw * 5 + ni) * 16;
                if (nc < 300) {
                    #pragma unroll
                    for (int mi = 0; mi < 4; ++mi)
                        #pragma unroll
                        for (int r = 0; r < 4; ++r)
                            sm.ep[mi * 16 + lq * 4 + r][nc + lr] = acc[mi][ni][r];
                }
            }
        }
        __syncthreads();

        #pragma unroll 1
        for (int t = tid; t < 64 * NOUT; t += 512) {
            int row = t / NOUT, o = t % NOUT;
            float xi[NEXP], miu_v[NEXP];
            float mx = -1e30f;
            #pragma unroll
            for (int e = 0; e < NEXP; ++e) {
                miu_v[e] = sm.ep[row][e * NOUT + o]       + eb[e * NOUT + o];
                xi[e]    = sm.ep[row][150 + e * NOUT + o] + gb[e * NOUT + o];
                mx = fmaxf(mx, xi[e]);
            }
            float s = 0.f, v = 0.f;
            #pragma unroll
            for (int e = 0; e < NEXP; ++e) {
                float g2 = __expf(xi[e] - mx);
                s += g2;
                v += g2 * miu_v[e];
            }
            out[(row0 + g * 64 + row) * NOUT + o] = v / s;
        }
        __syncthreads();
    }
}

extern "C" void kernel_launch(void* const* d_in, const int* in_sizes, int n_in,
                              void* d_out, int out_size, void* d_ws, size_t ws_size,
                              hipStream_t stream) {
    const float* x  = (const float*)d_in[0];
    const float* ew = (const float*)d_in[1];
    const float* eb = (const float*)d_in[2];
    const float* gw = (const float*)d_in[3];
    const float* gb = (const float*)d_in[4];
    float* out = (float*)d_out;
    unsigned short* ws = (unsigned short*)d_ws;   // needs NKS*WROWS*BK*2 = 640 KB

    wconv_kernel<<<160, 256, 0, stream>>>(ew, gw, ws);
    moe_kernel<<<65536 / BM, 512, 0, stream>>>(x, ws, eb, gb, out);
}

// Round 4
// 416.318 us; speedup vs baseline: 1.8237x; 1.2236x over previous
//
#include <hip/hip_runtime.h>

#define KDIM 1024
#define NOUT 15
#define NEXP 10
#define BM   64
#define BK   32
#define NKS  32            // KDIM / BK
#define QPT  20            // 1KB DMA units per k-slab: (global n-tile 0..9) x (kt 0..1)
#define SCOL 305           // epilogue scratch stride (fp32)

typedef short bf16x8 __attribute__((ext_vector_type(8)));
typedef float f32x16 __attribute__((ext_vector_type(16)));

// round-to-nearest-even fp32 -> bf16 pair packed into one dword
__device__ __forceinline__ unsigned f2bf2(float a, float b) {
    unsigned ua = __float_as_uint(a);
    unsigned ub = __float_as_uint(b);
    ua = (ua + 0x7FFFu + ((ua >> 16) & 1u)) >> 16;
    ub = (ub + 0x7FFFu + ((ub >> 16) & 1u)) & 0xFFFF0000u;
    return ua | ub;
}

__device__ __forceinline__ void dma16(const void* g, void* l) {
    __builtin_amdgcn_global_load_lds(
        (const __attribute__((address_space(1))) unsigned int*)g,
        (__attribute__((address_space(3))) unsigned int*)l, 16, 0, 0);
}

// ---- pre-pass: W (expert+gate) fp32 -> bf16 workspace in exact B-fragment order ----
// unit U (16B, 8 bf16): L = U&63, q = (U>>6)%QPT, ks = U/(QPT*64)
//   nt = q>>1 (global n-tile), kt = q&1
//   B-frag lane L holds W[row = nt*32 + (L&31)][k = ks*32 + kt*16 + (L>>5)*8 + 0..7]
__global__ void wconv_kernel(const float* __restrict__ ew,
                             const float* __restrict__ gw,
                             unsigned short* __restrict__ ws)
{
    int U  = blockIdx.x * 256 + threadIdx.x;    // 0 .. 40959
    int L  = U & 63;
    int q  = (U >> 6) % QPT;
    int ks = U / (QPT * 64);
    int nt = q >> 1, kt = q & 1;
    int wrow = nt * 32 + (L & 31);
    int wcol = ks * 32 + kt * 16 + (L >> 5) * 8;
    float4 a = {0.f,0.f,0.f,0.f}, b = {0.f,0.f,0.f,0.f};
    if (wrow < 150) {
        a = *(const float4*)(ew + wrow * KDIM + wcol);
        b = *(const float4*)(ew + wrow * KDIM + wcol + 4);
    } else if (wrow < 300) {
        a = *(const float4*)(gw + (wrow - 150) * KDIM + wcol);
        b = *(const float4*)(gw + (wrow - 150) * KDIM + wcol + 4);
    }
    uint4 o;
    o.x = f2bf2(a.x, a.y); o.y = f2bf2(a.z, a.w);
    o.z = f2bf2(b.x, b.y); o.w = f2bf2(b.z, b.w);
    *(uint4*)(ws + (size_t)U * 8) = o;
}

__global__ void __launch_bounds__(256, 3)
moe_kernel(const float* __restrict__ x,
           const unsigned short* __restrict__ wsrc,
           const float* __restrict__ eb,
           const float* __restrict__ gb,
           float* __restrict__ out)
{
    __shared__ union {
        unsigned short wb[2][QPT * 512];   // 2 x 20KB double-buffered W slabs
        float ep[32][SCOL];                // 39040 B epilogue scratch (after K loop)
    } sm;                                  // 40960 B

    const int tid = threadIdx.x;
    const int wv  = tid >> 6;
    const int L   = tid & 63;
    const int mw  = wv >> 1;      // 0..1 : which 32-row half
    const int nw  = wv & 1;       // 0..1 : n-tiles nw*5 .. nw*5+4 (160 cols)
    const int ln  = L & 31;       // MFMA row (A) / col (B, C/D)
    const int lh  = L >> 5;       // k-half selector within fragment

    // this lane's X row pointer (frag k-offset baked in)
    const float* xrow = x + ((size_t)blockIdx.x * BM + mw * 32 + ln) * KDIM + lh * 8;

    f32x16 acc[5];
    #pragma unroll
    for (int nt = 0; nt < 5; ++nt)
        #pragma unroll
        for (int r = 0; r < 16; ++r)
            acc[nt][r] = 0.f;

    // ---- prologue: DMA W slab 0, load A slab 0 ----
    #pragma unroll
    for (int i = 0; i < 5; ++i) {
        int q = wv * 5 + i;
        dma16(wsrc + ((size_t)q * 64 + L) * 8, &sm.wb[0][q * 512]);
    }
    float4 xa[2][2];
    #pragma unroll
    for (int kt = 0; kt < 2; ++kt) {
        xa[kt][0] = *(const float4*)(xrow + kt * 16);
        xa[kt][1] = *(const float4*)(xrow + kt * 16 + 4);
    }
    __syncthreads();

    // ---- K loop: 32 slabs, W double-buffered, A register-prefetched ----
    #pragma unroll 2
    for (int ks = 0; ks < NKS; ++ks) {
        float4 xn[2][2];
        if (ks + 1 < NKS) {
            #pragma unroll
            for (int kt = 0; kt < 2; ++kt) {
                xn[kt][0] = *(const float4*)(xrow + (ks + 1) * 32 + kt * 16);
                xn[kt][1] = *(const float4*)(xrow + (ks + 1) * 32 + kt * 16 + 4);
            }
            #pragma unroll
            for (int i = 0; i < 5; ++i) {
                int q = wv * 5 + i;
                dma16(wsrc + (((size_t)(ks + 1) * QPT + q) * 64 + L) * 8,
                      &sm.wb[(ks + 1) & 1][q * 512]);
            }
        }

        bf16x8 af[2];
        #pragma unroll
        for (int kt = 0; kt < 2; ++kt) {
            union { unsigned u[4]; bf16x8 v; } pk;
            pk.u[0] = f2bf2(xa[kt][0].x, xa[kt][0].y);
            pk.u[1] = f2bf2(xa[kt][0].z, xa[kt][0].w);
            pk.u[2] = f2bf2(xa[kt][1].x, xa[kt][1].y);
            pk.u[3] = f2bf2(xa[kt][1].z, xa[kt][1].w);
            af[kt] = pk.v;
        }

        const unsigned short* wbuf = sm.wb[ks & 1];
        #pragma unroll
        for (int nt = 0; nt < 5; ++nt) {
            #pragma unroll
            for (int kt = 0; kt < 2; ++kt) {
                int q = (nw * 5 + nt) * 2 + kt;
                bf16x8 bf = *(const bf16x8*)&wbuf[q * 512 + L * 8];
                acc[nt] = __builtin_amdgcn_mfma_f32_32x32x16_bf16(af[kt], bf, acc[nt], 0, 0, 0);
            }
        }
        __syncthreads();

        #pragma unroll
        for (int kt = 0; kt < 2; ++kt) {
            xa[kt][0] = xn[kt][0];
            xa[kt][1] = xn[kt][1];
        }
    }

    // ---- epilogue: two 32-row phases through LDS scratch ----
    #pragma unroll 1
    for (int g = 0; g < 2; ++g) {
        if (mw == g) {
            // 32x32 C/D layout: col = lane&31, row = (reg&3) + 8*(reg>>2) + 4*(lane>>5)
            #pragma unroll
            for (int nt = 0; nt < 5; ++nt) {
                int col = nw * 160 + nt * 32 + ln;
                if (col < 300) {
                    #pragma unroll
                    for (int r = 0; r < 16; ++r)
                        sm.ep[(r & 3) + 8 * (r >> 2) + 4 * lh][col] = acc[nt][r];
                }
            }
        }
        __syncthreads();

        #pragma unroll 1
        for (int t = tid; t < 32 * NOUT; t += 256) {
            int row = t / NOUT, o = t % NOUT;
            float xi[NEXP], miu_v[NEXP];
            float mx = -1e30f;
            #pragma unroll
            for (int e = 0; e < NEXP; ++e) {
                miu_v[e] = sm.ep[row][e * NOUT + o]       + eb[e * NOUT + o];
                xi[e]    = sm.ep[row][150 + e * NOUT + o] + gb[e * NOUT + o];
                mx = fmaxf(mx, xi[e]);
            }
            float s = 0.f, v = 0.f;
            #pragma unroll
            for (int e = 0; e < NEXP; ++e) {
                float g2 = __expf(xi[e] - mx);
                s += g2;
                v += g2 * miu_v[e];
            }
            out[((size_t)blockIdx.x * BM + g * 32 + row) * NOUT + o] = v / s;
        }
        __syncthreads();
    }
}

extern "C" void kernel_launch(void* const* d_in, const int* in_sizes, int n_in,
                              void* d_out, int out_size, void* d_ws, size_t ws_size,
                              hipStream_t stream) {
    const float* x  = (const float*)d_in[0];
    const float* ew = (const float*)d_in[1];
    const float* eb = (const float*)d_in[2];
    const float* gw = (const float*)d_in[3];
    const float* gb = (const float*)d_in[4];
    float* out = (float*)d_out;
    unsigned short* ws = (unsigned short*)d_ws;   // NKS*QPT*64*16B = 640 KB

    wconv_kernel<<<160, 256, 0, stream>>>(ew, gw, ws);
    moe_kernel<<<65536 / BM, 256, 0, stream>>>(x, ws, eb, gb, out);
}